// Round 10
// baseline (202.998 us; speedup 1.0000x reference)
//
#include <hip/hip_runtime.h>
#include <math.h>

typedef __attribute__((ext_vector_type(8))) short short8;   // 8 x bf16 (4 VGPRs)
typedef __attribute__((ext_vector_type(4))) float f32x4;    // MFMA acc
typedef __attribute__((ext_vector_type(2))) unsigned uint2v;

constexpr int B  = 8;
constexpr int N  = 1024;
constexpr int D  = 512;
constexpr int H  = 8;
constexpr int DH = 64;
constexpr int M_ROWS = 8192;
constexpr float EPS_DIST = 1e-8f;
constexpr float EPS_LN   = 1e-5f;

// fp32 -> bf16 bits (RNE)
__device__ inline unsigned short bfbits(float f) {
    union { float f; unsigned u; } v; v.f = f;
    unsigned r = v.u + 0x7fffu + ((v.u >> 16) & 1u);
    return (unsigned short)(r >> 16);
}
__device__ inline float bf2f(unsigned short s) {
    union { unsigned u; float f; } v; v.u = ((unsigned)s) << 16; return v.f;
}

// async 16B global->LDS (per lane; LDS dest = wave-uniform base + lane*16)
__device__ inline void async_ld16(unsigned short* lds, const unsigned short* g) {
    __builtin_amdgcn_global_load_lds(
        (const __attribute__((address_space(1))) unsigned int*)(g),
        (__attribute__((address_space(3))) unsigned int*)(lds),
        16, 0, 0);
}

// ---------------------------------------------------------------------------
// Fused: blocks 0..255 transpose+convert the 4 weights to bf16 (lane index
// k-major -> coalesced writes); blocks 256.. do LN1 (x -> h bf16),
// wave-per-row, no LDS, no barriers.
// ---------------------------------------------------------------------------
__global__ __launch_bounds__(256) void prep_kernel(const float* __restrict__ Wq,
                                                   const float* __restrict__ Wk,
                                                   const float* __restrict__ Wv,
                                                   const float* __restrict__ Wo,
                                                   unsigned short* __restrict__ WtAll,
                                                   const float* __restrict__ x,
                                                   const float* __restrict__ ln1_g,
                                                   const float* __restrict__ ln1_b,
                                                   unsigned short* __restrict__ h_bf) {
    const int bxg = blockIdx.x;
    if (bxg < 256) {
        int sub = bxg >> 6;
        const float* W = sub == 0 ? Wq : sub == 1 ? Wk : sub == 2 ? Wv : Wo;
        unsigned short* Wt = WtAll + (size_t)sub * 262144;
        int t = (bxg & 63) * 256 + threadIdx.x;
        int tk = t & 127, tn = t >> 7;     // k-major lanes: coalesced WRITES
        int k = tk * 4, n = tn * 4;
        float4 r0 = *(const float4*)&W[(size_t)(k + 0) * 512 + n];
        float4 r1 = *(const float4*)&W[(size_t)(k + 1) * 512 + n];
        float4 r2 = *(const float4*)&W[(size_t)(k + 2) * 512 + n];
        float4 r3 = *(const float4*)&W[(size_t)(k + 3) * 512 + n];
        ushort4 c;
        c.x = bfbits(r0.x); c.y = bfbits(r1.x); c.z = bfbits(r2.x); c.w = bfbits(r3.x);
        *(ushort4*)&Wt[(size_t)(n + 0) * 512 + k] = c;
        c.x = bfbits(r0.y); c.y = bfbits(r1.y); c.z = bfbits(r2.y); c.w = bfbits(r3.y);
        *(ushort4*)&Wt[(size_t)(n + 1) * 512 + k] = c;
        c.x = bfbits(r0.z); c.y = bfbits(r1.z); c.z = bfbits(r2.z); c.w = bfbits(r3.z);
        *(ushort4*)&Wt[(size_t)(n + 2) * 512 + k] = c;
        c.x = bfbits(r0.w); c.y = bfbits(r1.w); c.z = bfbits(r2.w); c.w = bfbits(r3.w);
        *(ushort4*)&Wt[(size_t)(n + 3) * 512 + k] = c;
    } else {
        const int w = threadIdx.x >> 6, lane = threadIdx.x & 63;
        const int row = (bxg - 256) * 4 + w;
        const float4* xr = (const float4*)(x + (size_t)row * D);
        float4 a = xr[lane], b2 = xr[lane + 64];
        float s = a.x + a.y + a.z + a.w + b2.x + b2.y + b2.z + b2.w;
        #pragma unroll
        for (int o = 1; o < 64; o <<= 1) s += __shfl_xor(s, o, 64);
        const float mu = s * (1.0f / 512.0f);
        float d0 = a.x - mu, d1 = a.y - mu, d2 = a.z - mu, d3 = a.w - mu;
        float e0 = b2.x - mu, e1 = b2.y - mu, e2 = b2.z - mu, e3 = b2.w - mu;
        float vs = d0*d0 + d1*d1 + d2*d2 + d3*d3 + e0*e0 + e1*e1 + e2*e2 + e3*e3;
        #pragma unroll
        for (int o = 1; o < 64; o <<= 1) vs += __shfl_xor(vs, o, 64);
        const float rstd = rsqrtf(vs * (1.0f / 512.0f) + EPS_LN);
        const float4* g4 = (const float4*)ln1_g;
        const float4* b4 = (const float4*)ln1_b;
        float4 ga = g4[lane], gb = g4[lane + 64];
        float4 ba = b4[lane], bb = b4[lane + 64];
        ushort4 u;
        u.x = bfbits(d0 * rstd * ga.x + ba.x);
        u.y = bfbits(d1 * rstd * ga.y + ba.y);
        u.z = bfbits(d2 * rstd * ga.z + ba.z);
        u.w = bfbits(d3 * rstd * ga.w + ba.w);
        *(ushort4*)&h_bf[(size_t)row * 512 + lane * 4] = u;
        u.x = bfbits(e0 * rstd * gb.x + bb.x);
        u.y = bfbits(e1 * rstd * gb.y + bb.y);
        u.z = bfbits(e2 * rstd * gb.z + bb.z);
        u.w = bfbits(e3 * rstd * gb.w + bb.w);
        *(ushort4*)&h_bf[(size_t)row * 512 + 256 + lane * 4] = u;
    }
}

// ---------------------------------------------------------------------------
// 128x128-tile bf16 MFMA GEMM, BK=64, MODE 1 (fused QKV, N=1536):
// Q,K -> [bh][n][dh] (LDS re-tile -> coalesced 16B stores) + sumsq,
// V -> [bh][dh][n] via LDS transpose.
// XOR-swizzled LDS staging (pre-swizzled global_load_lds source) ->
// conflict-free ds_read_b128 fragment reads.
// ---------------------------------------------------------------------------
template <int MODE, int MT>
__global__ __launch_bounds__(256) void gemm128(const unsigned short* __restrict__ A,
                                               const unsigned short* __restrict__ Wt,
                                               const float* __restrict__ bias0,
                                               const float* __restrict__ bias1,
                                               const float* __restrict__ bias2,
                                               void* __restrict__ o0,
                                               unsigned short* __restrict__ Ko,
                                               unsigned short* __restrict__ Vo,
                                               float* __restrict__ sq0,
                                               float* __restrict__ sq1) {
    constexpr int RB = M_ROWS / MT;
    constexpr int NI = MT / 32;
    constexpr int ASZ = MT * 64, BSZ = 128 * 64;
    constexpr int SMSZ = (MODE == 1) ? ((ASZ + BSZ > 18432) ? ASZ + BSZ : 18432)
                                     : (ASZ + BSZ);
    __shared__ unsigned short smem[SMSZ];
    unsigned short* As = smem;
    unsigned short* Bs = smem + ASZ;

    const int id = blockIdx.x;
    const int by = id & (RB - 1), bx = id / RB;
    const int tid = threadIdx.x;
    const int lane = tid & 63, wv = tid >> 6;
    const int quad = lane >> 4, l15 = lane & 15;
    const int row0 = by * MT, col0 = bx * 128;
    const int wm = (wv & 1) * (MT / 2), wn = (wv >> 1) * 64;
    const int fsw = (l15 & 7) << 3;            // fragment-read swizzle

    f32x4 acc[NI][4];
    #pragma unroll
    for (int i = 0; i < NI; ++i)
        #pragma unroll
        for (int j = 0; j < 4; ++j) acc[i][j] = (f32x4){0.f, 0.f, 0.f, 0.f};

    const unsigned short* Ag = A  + (size_t)row0 * 512;
    const unsigned short* Bg = Wt + (size_t)col0 * 512;

    for (int k0 = 0; k0 < 512; k0 += 64) {
        __syncthreads();
        #pragma unroll
        for (int c = 0; c < ASZ / 2048; ++c) {
            int fu = c * 2048 + tid * 8;
            int r = fu >> 6, ko = fu & 63;
            async_ld16(As + fu, Ag + (size_t)r * 512 + k0 + (ko ^ ((r & 7) << 3)));
        }
        #pragma unroll
        for (int c = 0; c < BSZ / 2048; ++c) {
            int fu = c * 2048 + tid * 8;
            int r = fu >> 6, ko = fu & 63;
            async_ld16(Bs + fu, Bg + (size_t)r * 512 + k0 + (ko ^ ((r & 7) << 3)));
        }
        __syncthreads();

        #pragma unroll
        for (int ks = 0; ks < 2; ++ks) {
            short8 af[NI], bf[4];
            #pragma unroll
            for (int i = 0; i < NI; ++i)
                af[i] = *(const short8*)&As[(wm + i * 16 + l15) * 64 +
                                            ((ks * 32 + quad * 8) ^ fsw)];
            #pragma unroll
            for (int j = 0; j < 4; ++j)
                bf[j] = *(const short8*)&Bs[(wn + j * 16 + l15) * 64 +
                                            ((ks * 32 + quad * 8) ^ fsw)];
            #pragma unroll
            for (int i = 0; i < NI; ++i)
                #pragma unroll
                for (int j = 0; j < 4; ++j)
                    acc[i][j] = __builtin_amdgcn_mfma_f32_16x16x32_bf16(af[i], bf[j], acc[i][j], 0, 0, 0);
        }
    }

    if (MODE == 0) {
        unsigned short* C = (unsigned short*)o0;
        #pragma unroll
        for (int i = 0; i < NI; ++i)
            #pragma unroll
            for (int j = 0; j < 4; ++j) {
                int col = col0 + wn + j * 16 + l15;
                float bv = bias0[col];
                #pragma unroll
                for (int r = 0; r < 4; ++r) {
                    int row = row0 + wm + i * 16 + quad * 4 + r;
                    C[(size_t)row * 512 + col] = bfbits(acc[i][j][r] + bv);
                }
            }
    } else {
        const int colg = col0 + wn;
        const int seg = colg >> 9;                 // 0=Q 1=K 2=V
        const int hh = (colg & 511) >> 6;
        const float* bias = seg == 0 ? bias0 : seg == 1 ? bias1 : bias2;

        __syncthreads();   // seg is block-uniform; all As/Bs reads complete
        unsigned short* T = smem + wv * 4608;      // per-wave [64][72]

        if (seg < 2) {
            unsigned short* dst = seg == 0 ? (unsigned short*)o0 : Ko;
            float* sq = seg == 0 ? sq0 : sq1;
            #pragma unroll
            for (int i = 0; i < NI; ++i) {
                const int m0 = row0 + wm + i * 16 + quad * 4;
                float ss[4] = {0.f, 0.f, 0.f, 0.f};
                #pragma unroll
                for (int j = 0; j < 4; ++j) {
                    float bvj = bias[hh * 64 + j * 16 + l15];
                    #pragma unroll
                    for (int r = 0; r < 4; ++r) {
                        float v = acc[i][j][r] + bvj;
                        unsigned short ub = bfbits(v);
                        float vr = bf2f(ub);
                        ss[r] += vr * vr;
                        T[(i * 16 + quad * 4 + r) * 72 + j * 16 + l15] = ub;
                    }
                }
                #pragma unroll
                for (int r = 0; r < 4; ++r) {
                    float s = ss[r];
                    s += __shfl_xor(s, 1, 64);
                    s += __shfl_xor(s, 2, 64);
                    s += __shfl_xor(s, 4, 64);
                    s += __shfl_xor(s, 8, 64);
                    if (l15 == 0) {
                        int m = m0 + r;
                        sq[(size_t)((m >> 10) * 8 + hh) * 1024 + (m & 1023)] = s;
                    }
                }
            }
            // coalesced store: wave tile = 64 rows (n) x 64 cols (dh)
            const int b_ = (row0 + wm) >> 10;
            const int nbase = (row0 + wm) & 1023;
            unsigned short* Dg = dst + ((size_t)((b_ * 8 + hh) * 1024 + nbase)) * 64;
            #pragma unroll
            for (int it = 0; it < 8; ++it) {
                int ml = it * 8 + (lane >> 3);
                int dl = (lane & 7) * 8;
                uint4 v = *(const uint4*)&T[ml * 72 + dl];
                *(uint4*)&Dg[(size_t)ml * 64 + dl] = v;
            }
        } else {
            // V: transpose through per-wave LDS region, then coalesced stores
            #pragma unroll
            for (int i = 0; i < NI; ++i)
                #pragma unroll
                for (int j = 0; j < 4; ++j) {
                    float bvj = bias[hh * 64 + j * 16 + l15];
                    ushort4 pk;
                    pk.x = bfbits(acc[i][j][0] + bvj);
                    pk.y = bfbits(acc[i][j][1] + bvj);
                    pk.z = bfbits(acc[i][j][2] + bvj);
                    pk.w = bfbits(acc[i][j][3] + bvj);
                    *(ushort4*)&T[(j * 16 + l15) * 72 + i * 16 + quad * 4] = pk;
                }
            const int b_ = (row0 + wm) >> 10;
            const int nbase = (row0 + wm) & 1023;
            unsigned short* Vg = Vo + ((size_t)((b_ * 8 + hh) * 64)) * 1024 + nbase;
            #pragma unroll
            for (int it = 0; it < 8; ++it) {
                int dl = it * 8 + (lane >> 3);
                int nl = (lane & 7) * 8;
                uint4 v = *(const uint4*)&T[dl * 72 + nl];
                *(uint4*)&Vg[(size_t)dl * 1024 + nl] = v;
            }
        }
    }
}

// ---------------------------------------------------------------------------
// Fused output projection + residual + LN2 -> fp32 out. Tile 32 rows x
// FULL 512 cols (each block owns complete LN rows). Grid 256, 4 waves;
// wave w owns cols w*128..+128. Swizzled LDS staging (as gemm128).
// ---------------------------------------------------------------------------
__global__ __launch_bounds__(256) void projln_kernel(const unsigned short* __restrict__ A,
                                                     const unsigned short* __restrict__ Wt,
                                                     const float* __restrict__ bo,
                                                     const float* __restrict__ x,
                                                     const float* __restrict__ gamma,
                                                     const float* __restrict__ beta,
                                                     float* __restrict__ out) {
    __shared__ unsigned short smem[2048 + 32768];   // As[32][64] | Bs[512][64]
    __shared__ float st[128];                        // [4 waves][32 rows]
    unsigned short* As = smem;
    unsigned short* Bs = smem + 2048;

    const int tid = threadIdx.x;
    const int lane = tid & 63, w = tid >> 6;
    const int quad = lane >> 4, l15 = lane & 15;
    const int rows0 = blockIdx.x * 32;
    const int fsw = (l15 & 7) << 3;

    f32x4 acc[2][8];
    #pragma unroll
    for (int i = 0; i < 2; ++i)
        #pragma unroll
        for (int j = 0; j < 8; ++j) acc[i][j] = (f32x4){0.f, 0.f, 0.f, 0.f};

    const unsigned short* Ag = A + (size_t)rows0 * 512;
    const int sr = tid >> 3;                   // staging row within 32-chunk
    const int sko = (tid & 7) * 8;

    for (int k0 = 0; k0 < 512; k0 += 64) {
        __syncthreads();
        async_ld16(As + tid * 8,
                   Ag + (size_t)sr * 512 + k0 + (sko ^ ((sr & 7) << 3)));
        #pragma unroll
        for (int c = 0; c < 16; ++c) {
            int fu = c * 2048 + tid * 8;
            int r = c * 32 + sr;
            async_ld16(Bs + fu,
                       Wt + (size_t)r * 512 + k0 + (sko ^ ((r & 7) << 3)));
        }
        __syncthreads();

        #pragma unroll
        for (int ks = 0; ks < 2; ++ks) {
            short8 af[2], bf[8];
            #pragma unroll
            for (int i = 0; i < 2; ++i)
                af[i] = *(const short8*)&As[(i * 16 + l15) * 64 +
                                            ((ks * 32 + quad * 8) ^ fsw)];
            #pragma unroll
            for (int j = 0; j < 8; ++j)
                bf[j] = *(const short8*)&Bs[(w * 128 + j * 16 + l15) * 64 +
                                            ((ks * 32 + quad * 8) ^ fsw)];
            #pragma unroll
            for (int i = 0; i < 2; ++i)
                #pragma unroll
                for (int j = 0; j < 8; ++j)
                    acc[i][j] = __builtin_amdgcn_mfma_f32_16x16x32_bf16(af[i], bf[j], acc[i][j], 0, 0, 0);
        }
    }

    // ---- epilogue: y = acc + bias + x (overwrite acc), row sums ----
    float s1[2][4] = {{0.f, 0.f, 0.f, 0.f}, {0.f, 0.f, 0.f, 0.f}};
    #pragma unroll
    for (int i = 0; i < 2; ++i)
        #pragma unroll
        for (int j = 0; j < 8; ++j) {
            const int colj = w * 128 + j * 16 + l15;
            const float bvj = bo[colj];
            #pragma unroll
            for (int r = 0; r < 4; ++r) {
                const int row = i * 16 + quad * 4 + r;
                float y = acc[i][j][r] + bvj +
                          x[(size_t)(rows0 + row) * 512 + colj];
                acc[i][j][r] = y;
                s1[i][r] += y;
            }
        }
    #pragma unroll
    for (int i = 0; i < 2; ++i)
        #pragma unroll
        for (int r = 0; r < 4; ++r) {
            s1[i][r] += __shfl_xor(s1[i][r], 1, 64);
            s1[i][r] += __shfl_xor(s1[i][r], 2, 64);
            s1[i][r] += __shfl_xor(s1[i][r], 4, 64);
            s1[i][r] += __shfl_xor(s1[i][r], 8, 64);
        }
    if (l15 == 0) {
        #pragma unroll
        for (int i = 0; i < 2; ++i)
            #pragma unroll
            for (int r = 0; r < 4; ++r)
                st[w * 32 + i * 16 + quad * 4 + r] = s1[i][r];
    }
    __syncthreads();
    float mu[2][4];
    #pragma unroll
    for (int i = 0; i < 2; ++i)
        #pragma unroll
        for (int r = 0; r < 4; ++r) {
            int row = i * 16 + quad * 4 + r;
            mu[i][r] = (st[row] + st[32 + row] + st[64 + row] + st[96 + row]) *
                       (1.0f / 512.0f);
        }
    __syncthreads();    // all mu reads done before st rewrite

    float s2[2][4] = {{0.f, 0.f, 0.f, 0.f}, {0.f, 0.f, 0.f, 0.f}};
    #pragma unroll
    for (int i = 0; i < 2; ++i)
        #pragma unroll
        for (int j = 0; j < 8; ++j)
            #pragma unroll
            for (int r = 0; r < 4; ++r) {
                float d = acc[i][j][r] - mu[i][r];
                s2[i][r] += d * d;
            }
    #pragma unroll
    for (int i = 0; i < 2; ++i)
        #pragma unroll
        for (int r = 0; r < 4; ++r) {
            s2[i][r] += __shfl_xor(s2[i][r], 1, 64);
            s2[i][r] += __shfl_xor(s2[i][r], 2, 64);
            s2[i][r] += __shfl_xor(s2[i][r], 4, 64);
            s2[i][r] += __shfl_xor(s2[i][r], 8, 64);
        }
    if (l15 == 0) {
        #pragma unroll
        for (int i = 0; i < 2; ++i)
            #pragma unroll
            for (int r = 0; r < 4; ++r)
                st[w * 32 + i * 16 + quad * 4 + r] = s2[i][r];
    }
    __syncthreads();
    float rs[2][4];
    #pragma unroll
    for (int i = 0; i < 2; ++i)
        #pragma unroll
        for (int r = 0; r < 4; ++r) {
            int row = i * 16 + quad * 4 + r;
            float var = (st[row] + st[32 + row] + st[64 + row] + st[96 + row]) *
                        (1.0f / 512.0f);
            rs[i][r] = rsqrtf(var + EPS_LN);
        }

    #pragma unroll
    for (int i = 0; i < 2; ++i)
        #pragma unroll
        for (int j = 0; j < 8; ++j) {
            const int colj = w * 128 + j * 16 + l15;
            const float gl = gamma[colj], bl = beta[colj];
            #pragma unroll
            for (int r = 0; r < 4; ++r) {
                const int row = i * 16 + quad * 4 + r;
                out[(size_t)(rows0 + row) * 512 + colj] =
                    (acc[i][j][r] - mu[i][r]) * rs[i][r] * gl + bl;
            }
        }
}

// ---------------------------------------------------------------------------
// MFMA distance attention, v7: NO K/V LDS STAGING, NO BARRIERS.
// K/V (256KB per bh) is L2-resident (all 8 qb-blocks of a bh land on one
// XCD: ids differ by 64, 64%8==0). Waves read K/V fragments directly from
// global (16B coalesced, L2 hits) -> staging + 16 __syncthreads deleted;
// waves run fully decoupled (guide m169 precedent: +26% at this exact
// shape). LDS only for the per-wave epilogue re-tile (no barrier: within-
// wave write->read). Geometry: v5b (4 waves, 32 q/wave, grid 512).
// ---------------------------------------------------------------------------
__global__ __launch_bounds__(256, 2) void attn_kernel(const unsigned short* __restrict__ Q,
                                                      const unsigned short* __restrict__ K,
                                                      const unsigned short* __restrict__ Vt,
                                                      const float* __restrict__ qsq,
                                                      const float* __restrict__ ksq,
                                                      unsigned short* __restrict__ O) {
    __shared__ unsigned short T3all[4][2304];      // epilogue re-tile only

    const int id = blockIdx.x;
    const int bh = id & 63, qb = id >> 6;          // qb 0..7
    const int q0 = qb * 128;
    const int tid = threadIdx.x;
    const int lane = tid & 63, w = tid >> 6;
    const int quad = lane >> 4, l15 = lane & 15;
    const int b_ = bh >> 3, h_ = bh & 7;

    const unsigned short* Qb = Q  + (size_t)bh * N * DH;
    const unsigned short* Kb = K  + (size_t)bh * N * DH;
    const unsigned short* Vb = Vt + (size_t)bh * DH * N;
    const float* ksb = ksq + (size_t)bh * N;

    // Q fragments (B-operand: lane l15 = q col), pre-scaled by -2 (bf16-exact).
    short8 qf[2][2];
    #pragma unroll
    for (int qh = 0; qh < 2; ++qh) {
        const unsigned short* qp = Qb + (size_t)(q0 + w * 32 + qh * 16 + l15) * 64 + quad * 8;
        qf[qh][0] = *(const short8*)qp;
        qf[qh][1] = *(const short8*)(qp + 32);
        unsigned* qw = (unsigned*)&qf[qh][0];
        #pragma unroll
        for (int j = 0; j < 8; ++j) qw[j] = (qw[j] ^ 0x80008000u) + 0x00800080u;
    }
    float qe[2];
    qe[0] = qsq[bh * N + q0 + w * 32 + l15] + EPS_DIST;
    qe[1] = qsq[bh * N + q0 + w * 32 + 16 + l15] + EPS_DIST;

    const short8 onesf = {0x3F80, 0x3F80, 0x3F80, 0x3F80, 0x3F80, 0x3F80, 0x3F80, 0x3F80};

    f32x4 oacc[2][4];
    f32x4 dsum[2];
    #pragma unroll
    for (int qh = 0; qh < 2; ++qh) {
        dsum[qh] = (f32x4){0.f, 0.f, 0.f, 0.f};
        #pragma unroll
        for (int dt = 0; dt < 4; ++dt) oacc[qh][dt] = (f32x4){0.f, 0.f, 0.f, 0.f};
    }

    #pragma unroll 2
    for (int kt = 0; kt < 16; ++kt) {
        const int k0 = kt * 64;
        #pragma unroll
        for (int kc = 0; kc < 2; ++kc) {
            // ---- scores for keys [k0 + kc*32, +32): swapped QK^T ----
            unsigned Wp[2][2][2];
            #pragma unroll
            for (int kh = 0; kh < 2; ++kh) {
                const int kb = kc * 2 + kh;
                const unsigned short* kp = Kb + (size_t)(k0 + kb * 16 + l15) * 64 + quad * 8;
                short8 kf0 = *(const short8*)kp;
                short8 kf1 = *(const short8*)(kp + 32);
                f32x4 ks2 = *(const f32x4*)&ksb[k0 + kb * 16 + quad * 4];
                #pragma unroll
                for (int qh = 0; qh < 2; ++qh) {
                    f32x4 sa;
                    #pragma unroll
                    for (int r = 0; r < 4; ++r) sa[r] = ks2[r] + qe[qh];
                    sa = __builtin_amdgcn_mfma_f32_16x16x32_bf16(kf0, qf[qh][0], sa, 0, 0, 0);
                    sa = __builtin_amdgcn_mfma_f32_16x16x32_bf16(kf1, qf[qh][1], sa, 0, 0, 0);
                    float pr[4];
                    #pragma unroll
                    for (int r = 0; r < 4; ++r) {
                        float d2 = fmaxf(sa[r], EPS_DIST);
                        pr[r] = __expf(-__builtin_amdgcn_sqrtf(d2));
                    }
                    union { float f; unsigned u; } u0, u1, u2, u3;
                    u0.f = pr[0]; u1.f = pr[1]; u2.f = pr[2]; u3.f = pr[3];
                    Wp[qh][kh][0] = __builtin_amdgcn_perm(u1.u, u0.u, 0x07060302u);
                    Wp[qh][kh][1] = __builtin_amdgcn_perm(u3.u, u2.u, 0x07060302u);
                }
            }

            // ---- V fragments for this kc (direct from global, L2-hit) ----
            short8 vf[4];
            #pragma unroll
            for (int dt = 0; dt < 4; ++dt)
                vf[dt] = *(const short8*)&Vb[(size_t)(dt * 16 + l15) * N +
                                             k0 + kc * 32 + quad * 8];

            // ---- build pf in-register; denominator + PV on matrix pipe ----
            #pragma unroll
            for (int qh = 0; qh < 2; ++qh) {
                uint2v ya = __builtin_amdgcn_permlane32_swap(Wp[qh][0][0], Wp[qh][1][0], false, false);
                uint2v za = __builtin_amdgcn_permlane16_swap(ya.x, ya.y, false, false);
                uint2v yb = __builtin_amdgcn_permlane32_swap(Wp[qh][0][1], Wp[qh][1][1], false, false);
                uint2v zb = __builtin_amdgcn_permlane16_swap(yb.x, yb.y, false, false);
                union { unsigned wds[4]; short8 s; } pu;
                pu.wds[0] = za.x; pu.wds[1] = zb.x; pu.wds[2] = za.y; pu.wds[3] = zb.y;
                short8 pf = pu.s;
                dsum[qh] = __builtin_amdgcn_mfma_f32_16x16x32_bf16(pf, onesf, dsum[qh], 0, 0, 0);
                #pragma unroll
                for (int dt = 0; dt < 4; ++dt)
                    oacc[qh][dt] = __builtin_amdgcn_mfma_f32_16x16x32_bf16(pf, vf[dt], oacc[qh][dt], 0, 0, 0);
            }
        }
    }

    // epilogue: dsum already in C-layout (row = quad*4+r). Re-tile O through
    // per-wave LDS (within-wave write->read, no barrier) for 16B stores.
    unsigned short* T3 = &T3all[w][0];             // per-wave [32][72]
    #pragma unroll
    for (int qh = 0; qh < 2; ++qh) {
        f32x4 rv;
        #pragma unroll
        for (int r = 0; r < 4; ++r) rv[r] = __builtin_amdgcn_rcpf(dsum[qh][r]);
        #pragma unroll
        for (int dt = 0; dt < 4; ++dt)
            #pragma unroll
            for (int r = 0; r < 4; ++r)
                T3[(qh * 16 + quad * 4 + r) * 72 + dt * 16 + l15] =
                    bfbits(oacc[qh][dt][r] * rv[r]);
    }
    unsigned short* Og = O + ((size_t)(b_ * N + q0 + w * 32) * D) + h_ * DH;
    #pragma unroll
    for (int it = 0; it < 4; ++it) {
        int ml = it * 8 + (lane >> 3);
        int dl = (lane & 7) * 8;
        uint4 v = *(const uint4*)&T3[ml * 72 + dl];
        *(uint4*)&Og[(size_t)ml * D + dl] = v;
    }
}

// ---------------------------------------------------------------------------
extern "C" void kernel_launch(void* const* d_in, const int* in_sizes, int n_in,
                              void* d_out, int out_size, void* d_ws, size_t ws_size,
                              hipStream_t stream) {
    const float* x     = (const float*)d_in[0];
    const float* Wq    = (const float*)d_in[1];
    const float* Wk    = (const float*)d_in[2];
    const float* Wv    = (const float*)d_in[3];
    const float* Wo    = (const float*)d_in[4];
    const float* bq    = (const float*)d_in[5];
    const float* bk    = (const float*)d_in[6];
    const float* bv    = (const float*)d_in[7];
    const float* bo    = (const float*)d_in[8];
    const float* ln1_g = (const float*)d_in[9];
    const float* ln1_b = (const float*)d_in[10];
    const float* ln2_g = (const float*)d_in[11];
    const float* ln2_b = (const float*)d_in[12];
    float* out = (float*)d_out;

    unsigned short* WtAll = (unsigned short*)d_ws;    // [4][512][512] bf16
    unsigned short* h_bf  = WtAll + 4 * 262144;       // [8192][512]
    unsigned short* Qb    = h_bf + 4194304;           // [64][1024][64]
    unsigned short* Kb    = Qb + 4194304;
    unsigned short* Vtg   = Kb + 4194304;             // [64][64][1024] transposed
    unsigned short* Ob    = Vtg + 4194304;            // [8192][512]
    float* qsq = (float*)(Ob + 4194304);              // [65536]
    float* ksq = qsq + 65536;

    // 1) weights -> bf16^T  +  LN1 -> bf16 (fused launch, wave-per-row LN)
    prep_kernel<<<256 + M_ROWS / 4, 256, 0, stream>>>(Wq, Wk, Wv, Wo, WtAll,
                                                      x, ln1_g, ln1_b, h_bf);

    // 2) fused QKV projection (N=1536) + coalesced scatter + sum-squares
    gemm128<1, 128><<<768, 256, 0, stream>>>(h_bf, WtAll, bq, bk, bv,
                                             Qb, Kb, Vtg, qsq, ksq);

    // 3) MFMA distance attention -> Ob (v7: no staging, no barriers)
    attn_kernel<<<512, 256, 0, stream>>>(Qb, Kb, Vtg, qsq, ksq, Ob);

    // 4) fused output projection + residual + LN2 -> out
    projln_kernel<<<256, 256, 0, stream>>>(Ob, WtAll + 3 * 262144, bo,
                                           x, ln2_g, ln2_b, out);
}

// Round 11
// 170.641 us; speedup vs baseline: 1.1896x; 1.1896x over previous
//
#include <hip/hip_runtime.h>
#include <math.h>

typedef __attribute__((ext_vector_type(8))) short short8;   // 8 x bf16 (4 VGPRs)
typedef __attribute__((ext_vector_type(4))) float f32x4;    // MFMA acc
typedef __attribute__((ext_vector_type(2))) unsigned uint2v;

constexpr int B  = 8;
constexpr int N  = 1024;
constexpr int D  = 512;
constexpr int H  = 8;
constexpr int DH = 64;
constexpr int M_ROWS = 8192;
constexpr float EPS_DIST = 1e-8f;
constexpr float EPS_LN   = 1e-5f;

// fp32 -> bf16 bits (RNE)
__device__ inline unsigned short bfbits(float f) {
    union { float f; unsigned u; } v; v.f = f;
    unsigned r = v.u + 0x7fffu + ((v.u >> 16) & 1u);
    return (unsigned short)(r >> 16);
}
__device__ inline float bf2f(unsigned short s) {
    union { unsigned u; float f; } v; v.u = ((unsigned)s) << 16; return v.f;
}

// async 16B global->LDS (per lane; LDS dest = wave-uniform base + lane*16)
__device__ inline void async_ld16(unsigned short* lds, const unsigned short* g) {
    __builtin_amdgcn_global_load_lds(
        (const __attribute__((address_space(1))) unsigned int*)(g),
        (__attribute__((address_space(3))) unsigned int*)(lds),
        16, 0, 0);
}

// ---------------------------------------------------------------------------
// Fused: blocks 0..255 transpose+convert the 4 weights to bf16 (lane index
// k-major -> coalesced writes); blocks 256.. do LN1 (x -> h bf16),
// wave-per-row, no LDS, no barriers.
// ---------------------------------------------------------------------------
__global__ __launch_bounds__(256) void prep_kernel(const float* __restrict__ Wq,
                                                   const float* __restrict__ Wk,
                                                   const float* __restrict__ Wv,
                                                   const float* __restrict__ Wo,
                                                   unsigned short* __restrict__ WtAll,
                                                   const float* __restrict__ x,
                                                   const float* __restrict__ ln1_g,
                                                   const float* __restrict__ ln1_b,
                                                   unsigned short* __restrict__ h_bf) {
    const int bxg = blockIdx.x;
    if (bxg < 256) {
        int sub = bxg >> 6;
        const float* W = sub == 0 ? Wq : sub == 1 ? Wk : sub == 2 ? Wv : Wo;
        unsigned short* Wt = WtAll + (size_t)sub * 262144;
        int t = (bxg & 63) * 256 + threadIdx.x;
        int tk = t & 127, tn = t >> 7;     // k-major lanes: coalesced WRITES
        int k = tk * 4, n = tn * 4;
        float4 r0 = *(const float4*)&W[(size_t)(k + 0) * 512 + n];
        float4 r1 = *(const float4*)&W[(size_t)(k + 1) * 512 + n];
        float4 r2 = *(const float4*)&W[(size_t)(k + 2) * 512 + n];
        float4 r3 = *(const float4*)&W[(size_t)(k + 3) * 512 + n];
        ushort4 c;
        c.x = bfbits(r0.x); c.y = bfbits(r1.x); c.z = bfbits(r2.x); c.w = bfbits(r3.x);
        *(ushort4*)&Wt[(size_t)(n + 0) * 512 + k] = c;
        c.x = bfbits(r0.y); c.y = bfbits(r1.y); c.z = bfbits(r2.y); c.w = bfbits(r3.y);
        *(ushort4*)&Wt[(size_t)(n + 1) * 512 + k] = c;
        c.x = bfbits(r0.z); c.y = bfbits(r1.z); c.z = bfbits(r2.z); c.w = bfbits(r3.z);
        *(ushort4*)&Wt[(size_t)(n + 2) * 512 + k] = c;
        c.x = bfbits(r0.w); c.y = bfbits(r1.w); c.z = bfbits(r2.w); c.w = bfbits(r3.w);
        *(ushort4*)&Wt[(size_t)(n + 3) * 512 + k] = c;
    } else {
        const int w = threadIdx.x >> 6, lane = threadIdx.x & 63;
        const int row = (bxg - 256) * 4 + w;
        const float4* xr = (const float4*)(x + (size_t)row * D);
        float4 a = xr[lane], b2 = xr[lane + 64];
        float s = a.x + a.y + a.z + a.w + b2.x + b2.y + b2.z + b2.w;
        #pragma unroll
        for (int o = 1; o < 64; o <<= 1) s += __shfl_xor(s, o, 64);
        const float mu = s * (1.0f / 512.0f);
        float d0 = a.x - mu, d1 = a.y - mu, d2 = a.z - mu, d3 = a.w - mu;
        float e0 = b2.x - mu, e1 = b2.y - mu, e2 = b2.z - mu, e3 = b2.w - mu;
        float vs = d0*d0 + d1*d1 + d2*d2 + d3*d3 + e0*e0 + e1*e1 + e2*e2 + e3*e3;
        #pragma unroll
        for (int o = 1; o < 64; o <<= 1) vs += __shfl_xor(vs, o, 64);
        const float rstd = rsqrtf(vs * (1.0f / 512.0f) + EPS_LN);
        const float4* g4 = (const float4*)ln1_g;
        const float4* b4 = (const float4*)ln1_b;
        float4 ga = g4[lane], gb = g4[lane + 64];
        float4 ba = b4[lane], bb = b4[lane + 64];
        ushort4 u;
        u.x = bfbits(d0 * rstd * ga.x + ba.x);
        u.y = bfbits(d1 * rstd * ga.y + ba.y);
        u.z = bfbits(d2 * rstd * ga.z + ba.z);
        u.w = bfbits(d3 * rstd * ga.w + ba.w);
        *(ushort4*)&h_bf[(size_t)row * 512 + lane * 4] = u;
        u.x = bfbits(e0 * rstd * gb.x + bb.x);
        u.y = bfbits(e1 * rstd * gb.y + bb.y);
        u.z = bfbits(e2 * rstd * gb.z + bb.z);
        u.w = bfbits(e3 * rstd * gb.w + bb.w);
        *(ushort4*)&h_bf[(size_t)row * 512 + 256 + lane * 4] = u;
    }
}

// ---------------------------------------------------------------------------
// 128x128-tile bf16 MFMA GEMM, BK=64, MODE 1 (fused QKV, N=1536):
// Q,K -> [bh][n][dh] (LDS re-tile -> coalesced 16B stores) + sumsq,
// V -> [bh][dh][n] via LDS transpose.
// XOR-swizzled LDS staging (pre-swizzled global_load_lds source) ->
// conflict-free ds_read_b128 fragment reads.
// ---------------------------------------------------------------------------
template <int MODE, int MT>
__global__ __launch_bounds__(256) void gemm128(const unsigned short* __restrict__ A,
                                               const unsigned short* __restrict__ Wt,
                                               const float* __restrict__ bias0,
                                               const float* __restrict__ bias1,
                                               const float* __restrict__ bias2,
                                               void* __restrict__ o0,
                                               unsigned short* __restrict__ Ko,
                                               unsigned short* __restrict__ Vo,
                                               float* __restrict__ sq0,
                                               float* __restrict__ sq1) {
    constexpr int RB = M_ROWS / MT;
    constexpr int NI = MT / 32;
    constexpr int ASZ = MT * 64, BSZ = 128 * 64;
    constexpr int SMSZ = (MODE == 1) ? ((ASZ + BSZ > 18432) ? ASZ + BSZ : 18432)
                                     : (ASZ + BSZ);
    __shared__ unsigned short smem[SMSZ];
    unsigned short* As = smem;
    unsigned short* Bs = smem + ASZ;

    const int id = blockIdx.x;
    const int by = id & (RB - 1), bx = id / RB;
    const int tid = threadIdx.x;
    const int lane = tid & 63, wv = tid >> 6;
    const int quad = lane >> 4, l15 = lane & 15;
    const int row0 = by * MT, col0 = bx * 128;
    const int wm = (wv & 1) * (MT / 2), wn = (wv >> 1) * 64;
    const int fsw = (l15 & 7) << 3;            // fragment-read swizzle

    f32x4 acc[NI][4];
    #pragma unroll
    for (int i = 0; i < NI; ++i)
        #pragma unroll
        for (int j = 0; j < 4; ++j) acc[i][j] = (f32x4){0.f, 0.f, 0.f, 0.f};

    const unsigned short* Ag = A  + (size_t)row0 * 512;
    const unsigned short* Bg = Wt + (size_t)col0 * 512;

    for (int k0 = 0; k0 < 512; k0 += 64) {
        __syncthreads();
        #pragma unroll
        for (int c = 0; c < ASZ / 2048; ++c) {
            int fu = c * 2048 + tid * 8;
            int r = fu >> 6, ko = fu & 63;
            async_ld16(As + fu, Ag + (size_t)r * 512 + k0 + (ko ^ ((r & 7) << 3)));
        }
        #pragma unroll
        for (int c = 0; c < BSZ / 2048; ++c) {
            int fu = c * 2048 + tid * 8;
            int r = fu >> 6, ko = fu & 63;
            async_ld16(Bs + fu, Bg + (size_t)r * 512 + k0 + (ko ^ ((r & 7) << 3)));
        }
        __syncthreads();

        #pragma unroll
        for (int ks = 0; ks < 2; ++ks) {
            short8 af[NI], bf[4];
            #pragma unroll
            for (int i = 0; i < NI; ++i)
                af[i] = *(const short8*)&As[(wm + i * 16 + l15) * 64 +
                                            ((ks * 32 + quad * 8) ^ fsw)];
            #pragma unroll
            for (int j = 0; j < 4; ++j)
                bf[j] = *(const short8*)&Bs[(wn + j * 16 + l15) * 64 +
                                            ((ks * 32 + quad * 8) ^ fsw)];
            #pragma unroll
            for (int i = 0; i < NI; ++i)
                #pragma unroll
                for (int j = 0; j < 4; ++j)
                    acc[i][j] = __builtin_amdgcn_mfma_f32_16x16x32_bf16(af[i], bf[j], acc[i][j], 0, 0, 0);
        }
    }

    if (MODE == 0) {
        unsigned short* C = (unsigned short*)o0;
        #pragma unroll
        for (int i = 0; i < NI; ++i)
            #pragma unroll
            for (int j = 0; j < 4; ++j) {
                int col = col0 + wn + j * 16 + l15;
                float bv = bias0[col];
                #pragma unroll
                for (int r = 0; r < 4; ++r) {
                    int row = row0 + wm + i * 16 + quad * 4 + r;
                    C[(size_t)row * 512 + col] = bfbits(acc[i][j][r] + bv);
                }
            }
    } else {
        const int colg = col0 + wn;
        const int seg = colg >> 9;                 // 0=Q 1=K 2=V
        const int hh = (colg & 511) >> 6;
        const float* bias = seg == 0 ? bias0 : seg == 1 ? bias1 : bias2;

        __syncthreads();   // seg is block-uniform; all As/Bs reads complete
        unsigned short* T = smem + wv * 4608;      // per-wave [64][72]

        if (seg < 2) {
            unsigned short* dst = seg == 0 ? (unsigned short*)o0 : Ko;
            float* sq = seg == 0 ? sq0 : sq1;
            #pragma unroll
            for (int i = 0; i < NI; ++i) {
                const int m0 = row0 + wm + i * 16 + quad * 4;
                float ss[4] = {0.f, 0.f, 0.f, 0.f};
                #pragma unroll
                for (int j = 0; j < 4; ++j) {
                    float bvj = bias[hh * 64 + j * 16 + l15];
                    #pragma unroll
                    for (int r = 0; r < 4; ++r) {
                        float v = acc[i][j][r] + bvj;
                        unsigned short ub = bfbits(v);
                        float vr = bf2f(ub);
                        ss[r] += vr * vr;
                        T[(i * 16 + quad * 4 + r) * 72 + j * 16 + l15] = ub;
                    }
                }
                #pragma unroll
                for (int r = 0; r < 4; ++r) {
                    float s = ss[r];
                    s += __shfl_xor(s, 1, 64);
                    s += __shfl_xor(s, 2, 64);
                    s += __shfl_xor(s, 4, 64);
                    s += __shfl_xor(s, 8, 64);
                    if (l15 == 0) {
                        int m = m0 + r;
                        sq[(size_t)((m >> 10) * 8 + hh) * 1024 + (m & 1023)] = s;
                    }
                }
            }
            // coalesced store: wave tile = 64 rows (n) x 64 cols (dh)
            const int b_ = (row0 + wm) >> 10;
            const int nbase = (row0 + wm) & 1023;
            unsigned short* Dg = dst + ((size_t)((b_ * 8 + hh) * 1024 + nbase)) * 64;
            #pragma unroll
            for (int it = 0; it < 8; ++it) {
                int ml = it * 8 + (lane >> 3);
                int dl = (lane & 7) * 8;
                uint4 v = *(const uint4*)&T[ml * 72 + dl];
                *(uint4*)&Dg[(size_t)ml * 64 + dl] = v;
            }
        } else {
            // V: transpose through per-wave LDS region, then coalesced stores
            #pragma unroll
            for (int i = 0; i < NI; ++i)
                #pragma unroll
                for (int j = 0; j < 4; ++j) {
                    float bvj = bias[hh * 64 + j * 16 + l15];
                    ushort4 pk;
                    pk.x = bfbits(acc[i][j][0] + bvj);
                    pk.y = bfbits(acc[i][j][1] + bvj);
                    pk.z = bfbits(acc[i][j][2] + bvj);
                    pk.w = bfbits(acc[i][j][3] + bvj);
                    *(ushort4*)&T[(j * 16 + l15) * 72 + i * 16 + quad * 4] = pk;
                }
            const int b_ = (row0 + wm) >> 10;
            const int nbase = (row0 + wm) & 1023;
            unsigned short* Vg = Vo + ((size_t)((b_ * 8 + hh) * 64)) * 1024 + nbase;
            #pragma unroll
            for (int it = 0; it < 8; ++it) {
                int dl = it * 8 + (lane >> 3);
                int nl = (lane & 7) * 8;
                uint4 v = *(const uint4*)&T[dl * 72 + nl];
                *(uint4*)&Vg[(size_t)dl * 1024 + nl] = v;
            }
        }
    }
}

// ---------------------------------------------------------------------------
// Fused output projection + residual + LN2 -> fp32 out. Tile 32 rows x
// FULL 512 cols (each block owns complete LN rows). Grid 256, 4 waves;
// wave w owns cols w*128..+128. Swizzled LDS staging (as gemm128).
// ---------------------------------------------------------------------------
__global__ __launch_bounds__(256) void projln_kernel(const unsigned short* __restrict__ A,
                                                     const unsigned short* __restrict__ Wt,
                                                     const float* __restrict__ bo,
                                                     const float* __restrict__ x,
                                                     const float* __restrict__ gamma,
                                                     const float* __restrict__ beta,
                                                     float* __restrict__ out) {
    __shared__ unsigned short smem[2048 + 32768];   // As[32][64] | Bs[512][64]
    __shared__ float st[128];                        // [4 waves][32 rows]
    unsigned short* As = smem;
    unsigned short* Bs = smem + 2048;

    const int tid = threadIdx.x;
    const int lane = tid & 63, w = tid >> 6;
    const int quad = lane >> 4, l15 = lane & 15;
    const int rows0 = blockIdx.x * 32;
    const int fsw = (l15 & 7) << 3;

    f32x4 acc[2][8];
    #pragma unroll
    for (int i = 0; i < 2; ++i)
        #pragma unroll
        for (int j = 0; j < 8; ++j) acc[i][j] = (f32x4){0.f, 0.f, 0.f, 0.f};

    const unsigned short* Ag = A + (size_t)rows0 * 512;
    const int sr = tid >> 3;                   // staging row within 32-chunk
    const int sko = (tid & 7) * 8;

    for (int k0 = 0; k0 < 512; k0 += 64) {
        __syncthreads();
        async_ld16(As + tid * 8,
                   Ag + (size_t)sr * 512 + k0 + (sko ^ ((sr & 7) << 3)));
        #pragma unroll
        for (int c = 0; c < 16; ++c) {
            int fu = c * 2048 + tid * 8;
            int r = c * 32 + sr;
            async_ld16(Bs + fu,
                       Wt + (size_t)r * 512 + k0 + (sko ^ ((r & 7) << 3)));
        }
        __syncthreads();

        #pragma unroll
        for (int ks = 0; ks < 2; ++ks) {
            short8 af[2], bf[8];
            #pragma unroll
            for (int i = 0; i < 2; ++i)
                af[i] = *(const short8*)&As[(i * 16 + l15) * 64 +
                                            ((ks * 32 + quad * 8) ^ fsw)];
            #pragma unroll
            for (int j = 0; j < 8; ++j)
                bf[j] = *(const short8*)&Bs[(w * 128 + j * 16 + l15) * 64 +
                                            ((ks * 32 + quad * 8) ^ fsw)];
            #pragma unroll
            for (int i = 0; i < 2; ++i)
                #pragma unroll
                for (int j = 0; j < 8; ++j)
                    acc[i][j] = __builtin_amdgcn_mfma_f32_16x16x32_bf16(af[i], bf[j], acc[i][j], 0, 0, 0);
        }
    }

    // ---- epilogue: y = acc + bias + x (overwrite acc), row sums ----
    float s1[2][4] = {{0.f, 0.f, 0.f, 0.f}, {0.f, 0.f, 0.f, 0.f}};
    #pragma unroll
    for (int i = 0; i < 2; ++i)
        #pragma unroll
        for (int j = 0; j < 8; ++j) {
            const int colj = w * 128 + j * 16 + l15;
            const float bvj = bo[colj];
            #pragma unroll
            for (int r = 0; r < 4; ++r) {
                const int row = i * 16 + quad * 4 + r;
                float y = acc[i][j][r] + bvj +
                          x[(size_t)(rows0 + row) * 512 + colj];
                acc[i][j][r] = y;
                s1[i][r] += y;
            }
        }
    #pragma unroll
    for (int i = 0; i < 2; ++i)
        #pragma unroll
        for (int r = 0; r < 4; ++r) {
            s1[i][r] += __shfl_xor(s1[i][r], 1, 64);
            s1[i][r] += __shfl_xor(s1[i][r], 2, 64);
            s1[i][r] += __shfl_xor(s1[i][r], 4, 64);
            s1[i][r] += __shfl_xor(s1[i][r], 8, 64);
        }
    if (l15 == 0) {
        #pragma unroll
        for (int i = 0; i < 2; ++i)
            #pragma unroll
            for (int r = 0; r < 4; ++r)
                st[w * 32 + i * 16 + quad * 4 + r] = s1[i][r];
    }
    __syncthreads();
    float mu[2][4];
    #pragma unroll
    for (int i = 0; i < 2; ++i)
        #pragma unroll
        for (int r = 0; r < 4; ++r) {
            int row = i * 16 + quad * 4 + r;
            mu[i][r] = (st[row] + st[32 + row] + st[64 + row] + st[96 + row]) *
                       (1.0f / 512.0f);
        }
    __syncthreads();    // all mu reads done before st rewrite

    float s2[2][4] = {{0.f, 0.f, 0.f, 0.f}, {0.f, 0.f, 0.f, 0.f}};
    #pragma unroll
    for (int i = 0; i < 2; ++i)
        #pragma unroll
        for (int j = 0; j < 8; ++j)
            #pragma unroll
            for (int r = 0; r < 4; ++r) {
                float d = acc[i][j][r] - mu[i][r];
                s2[i][r] += d * d;
            }
    #pragma unroll
    for (int i = 0; i < 2; ++i)
        #pragma unroll
        for (int r = 0; r < 4; ++r) {
            s2[i][r] += __shfl_xor(s2[i][r], 1, 64);
            s2[i][r] += __shfl_xor(s2[i][r], 2, 64);
            s2[i][r] += __shfl_xor(s2[i][r], 4, 64);
            s2[i][r] += __shfl_xor(s2[i][r], 8, 64);
        }
    if (l15 == 0) {
        #pragma unroll
        for (int i = 0; i < 2; ++i)
            #pragma unroll
            for (int r = 0; r < 4; ++r)
                st[w * 32 + i * 16 + quad * 4 + r] = s2[i][r];
    }
    __syncthreads();
    float rs[2][4];
    #pragma unroll
    for (int i = 0; i < 2; ++i)
        #pragma unroll
        for (int r = 0; r < 4; ++r) {
            int row = i * 16 + quad * 4 + r;
            float var = (st[row] + st[32 + row] + st[64 + row] + st[96 + row]) *
                        (1.0f / 512.0f);
            rs[i][r] = rsqrtf(var + EPS_LN);
        }

    #pragma unroll
    for (int i = 0; i < 2; ++i)
        #pragma unroll
        for (int j = 0; j < 8; ++j) {
            const int colj = w * 128 + j * 16 + l15;
            const float gl = gamma[colj], bl = beta[colj];
            #pragma unroll
            for (int r = 0; r < 4; ++r) {
                const int row = i * 16 + quad * 4 + r;
                out[(size_t)(rows0 + row) * 512 + colj] =
                    (acc[i][j][r] - mu[i][r]) * rs[i][r] * gl + bl;
            }
        }
}

// ---------------------------------------------------------------------------
// MFMA distance attention, v5b (measured best). 4 waves/block, 128 q rows
// (32 q/wave), grid 512 -> 2 blocks/CU. global_load_lds staging (linear LDS
// dest + inverse-swizzled global src); swapped QK^T, in-register P, MFMA
// denominator, coalesced O store.
// ---------------------------------------------------------------------------
__global__ __launch_bounds__(256, 2) void attn_kernel(const unsigned short* __restrict__ Q,
                                                      const unsigned short* __restrict__ K,
                                                      const unsigned short* __restrict__ Vt,
                                                      const float* __restrict__ qsq,
                                                      const float* __restrict__ ksq,
                                                      unsigned short* __restrict__ O) {
    __shared__ unsigned short smem[2 * 4096 + 2 * 4096 + 256];
    unsigned short* KsB = smem;                    // [2][64][64] swizzled
    unsigned short* VsB = smem + 8192;             // [2][64][64] swizzled
    float* ksq_s = (float*)(smem + 16384);         // [2][64]

    const int id = blockIdx.x;
    const int bh = id & 63, qb = id >> 6;          // qb 0..7
    const int q0 = qb * 128;
    const int tid = threadIdx.x;
    const int lane = tid & 63, w = tid >> 6;
    const int quad = lane >> 4, l15 = lane & 15;
    const int b_ = bh >> 3, h_ = bh & 7;

    const unsigned short* Qb = Q  + (size_t)bh * N * DH;
    const unsigned short* Kb = K  + (size_t)bh * N * DH;
    const unsigned short* Vb = Vt + (size_t)bh * DH * N;

    // Q fragments (B-operand: lane l15 = q col), pre-scaled by -2 (bf16-exact).
    short8 qf[2][2];
    #pragma unroll
    for (int qh = 0; qh < 2; ++qh) {
        const unsigned short* qp = Qb + (size_t)(q0 + w * 32 + qh * 16 + l15) * 64 + quad * 8;
        qf[qh][0] = *(const short8*)qp;
        qf[qh][1] = *(const short8*)(qp + 32);
        unsigned* qw = (unsigned*)&qf[qh][0];
        #pragma unroll
        for (int j = 0; j < 8; ++j) qw[j] = (qw[j] ^ 0x80008000u) + 0x00800080u;
    }
    float qe[2];
    qe[0] = qsq[bh * N + q0 + w * 32 + l15] + EPS_DIST;
    qe[1] = qsq[bh * N + q0 + w * 32 + 16 + l15] + EPS_DIST;

    const short8 onesf = {0x3F80, 0x3F80, 0x3F80, 0x3F80, 0x3F80, 0x3F80, 0x3F80, 0x3F80};

    f32x4 oacc[2][4];
    f32x4 dsum[2];
    #pragma unroll
    for (int qh = 0; qh < 2; ++qh) {
        dsum[qh] = (f32x4){0.f, 0.f, 0.f, 0.f};
        #pragma unroll
        for (int dt = 0; dt < 4; ++dt) oacc[qh][dt] = (f32x4){0.f, 0.f, 0.f, 0.f};
    }

    // staging geometry: LDS element e = c*2048 + tid*8 -> row = c*32 + tid>>3,
    // linear col (tid&7)*8; global source col pre-swizzled (involution).
    const int srow = tid >> 3;                     // row within 32-row chunk
    const int scol = ((tid & 7) * 8) ^ ((srow & 7) << 3);

    #pragma unroll
    for (int c = 0; c < 2; ++c) {
        const int e = c * 2048 + tid * 8;
        const int row = srow + c * 32;
        async_ld16(KsB + e, Kb + (size_t)row * 64 + scol);
        async_ld16(VsB + e, Vb + (size_t)row * N + scol);
    }
    if (tid < 64) ksq_s[tid] = ksq[bh * N + tid];
    __syncthreads();

    for (int kt = 0; kt < 16; ++kt) {
        const int cur = kt & 1;
        float ksreg = 0.f;
        if (kt < 15) {
            const int t64 = (kt + 1) * 64;
            #pragma unroll
            for (int c = 0; c < 2; ++c) {
                const int e = (cur ^ 1) * 4096 + c * 2048 + tid * 8;
                const int row = srow + c * 32;
                const int cg = ((tid & 7) * 8) ^ ((row & 7) << 3);
                async_ld16(KsB + e, Kb + (size_t)(t64 + row) * 64 + cg);
                async_ld16(VsB + e, Vb + (size_t)row * N + t64 + cg);
            }
            if (tid < 64) ksreg = ksq[bh * N + t64 + tid];
        }

        #pragma unroll
        for (int kc = 0; kc < 2; ++kc) {
            // ---- scores for keys [kt*64 + kc*32, +32): swapped QK^T ----
            unsigned Wp[2][2][2];
            #pragma unroll
            for (int kh = 0; kh < 2; ++kh) {
                const int kb = kc * 2 + kh;
                const int krow = kb * 16 + l15;
                const int ksw = (krow & 7) << 3;
                const unsigned short* kbase = KsB + cur * 4096 + krow * 64;
                short8 kf0 = *(const short8*)&kbase[(quad * 8) ^ ksw];
                short8 kf1 = *(const short8*)&kbase[(32 + quad * 8) ^ ksw];
                f32x4 ks2 = *(const f32x4*)&ksq_s[cur * 64 + kb * 16 + quad * 4];
                #pragma unroll
                for (int qh = 0; qh < 2; ++qh) {
                    f32x4 sa;
                    #pragma unroll
                    for (int r = 0; r < 4; ++r) sa[r] = ks2[r] + qe[qh];
                    sa = __builtin_amdgcn_mfma_f32_16x16x32_bf16(kf0, qf[qh][0], sa, 0, 0, 0);
                    sa = __builtin_amdgcn_mfma_f32_16x16x32_bf16(kf1, qf[qh][1], sa, 0, 0, 0);
                    float pr[4];
                    #pragma unroll
                    for (int r = 0; r < 4; ++r) {
                        float d2 = fmaxf(sa[r], EPS_DIST);
                        pr[r] = __expf(-__builtin_amdgcn_sqrtf(d2));
                    }
                    union { float f; unsigned u; } u0, u1, u2, u3;
                    u0.f = pr[0]; u1.f = pr[1]; u2.f = pr[2]; u3.f = pr[3];
                    Wp[qh][kh][0] = __builtin_amdgcn_perm(u1.u, u0.u, 0x07060302u);
                    Wp[qh][kh][1] = __builtin_amdgcn_perm(u3.u, u2.u, 0x07060302u);
                }
            }

            // ---- V fragments for this kc ----
            short8 vf[4];
            #pragma unroll
            for (int dt = 0; dt < 4; ++dt) {
                const int vrow = dt * 16 + l15;
                vf[dt] = *(const short8*)&VsB[cur * 4096 + vrow * 64 +
                                              ((kc * 32 + quad * 8) ^ ((vrow & 7) << 3))];
            }

            // ---- build pf in-register; denominator + PV on matrix pipe ----
            #pragma unroll
            for (int qh = 0; qh < 2; ++qh) {
                uint2v ya = __builtin_amdgcn_permlane32_swap(Wp[qh][0][0], Wp[qh][1][0], false, false);
                uint2v za = __builtin_amdgcn_permlane16_swap(ya.x, ya.y, false, false);
                uint2v yb = __builtin_amdgcn_permlane32_swap(Wp[qh][0][1], Wp[qh][1][1], false, false);
                uint2v zb = __builtin_amdgcn_permlane16_swap(yb.x, yb.y, false, false);
                union { unsigned wds[4]; short8 s; } pu;
                pu.wds[0] = za.x; pu.wds[1] = zb.x; pu.wds[2] = za.y; pu.wds[3] = zb.y;
                short8 pf = pu.s;
                dsum[qh] = __builtin_amdgcn_mfma_f32_16x16x32_bf16(pf, onesf, dsum[qh], 0, 0, 0);
                #pragma unroll
                for (int dt = 0; dt < 4; ++dt)
                    oacc[qh][dt] = __builtin_amdgcn_mfma_f32_16x16x32_bf16(pf, vf[dt], oacc[qh][dt], 0, 0, 0);
            }
        }

        if (kt < 15 && tid < 64) ksq_s[(cur ^ 1) * 64 + tid] = ksreg;
        __syncthreads();
    }

    // epilogue: dsum already in C-layout (row = quad*4+r). Re-tile O through
    // now-dead smem (all waves past final barrier) for coalesced 16B stores.
    unsigned short* T3 = smem + w * 2304;          // per-wave [32][72]
    #pragma unroll
    for (int qh = 0; qh < 2; ++qh) {
        f32x4 rv;
        #pragma unroll
        for (int r = 0; r < 4; ++r) rv[r] = __builtin_amdgcn_rcpf(dsum[qh][r]);
        #pragma unroll
        for (int dt = 0; dt < 4; ++dt)
            #pragma unroll
            for (int r = 0; r < 4; ++r)
                T3[(qh * 16 + quad * 4 + r) * 72 + dt * 16 + l15] =
                    bfbits(oacc[qh][dt][r] * rv[r]);
    }
    unsigned short* Og = O + ((size_t)(b_ * N + q0 + w * 32) * D) + h_ * DH;
    #pragma unroll
    for (int it = 0; it < 4; ++it) {
        int ml = it * 8 + (lane >> 3);
        int dl = (lane & 7) * 8;
        uint4 v = *(const uint4*)&T3[ml * 72 + dl];
        *(uint4*)&Og[(size_t)ml * D + dl] = v;
    }
}

// ---------------------------------------------------------------------------
extern "C" void kernel_launch(void* const* d_in, const int* in_sizes, int n_in,
                              void* d_out, int out_size, void* d_ws, size_t ws_size,
                              hipStream_t stream) {
    const float* x     = (const float*)d_in[0];
    const float* Wq    = (const float*)d_in[1];
    const float* Wk    = (const float*)d_in[2];
    const float* Wv    = (const float*)d_in[3];
    const float* Wo    = (const float*)d_in[4];
    const float* bq    = (const float*)d_in[5];
    const float* bk    = (const float*)d_in[6];
    const float* bv    = (const float*)d_in[7];
    const float* bo    = (const float*)d_in[8];
    const float* ln1_g = (const float*)d_in[9];
    const float* ln1_b = (const float*)d_in[10];
    const float* ln2_g = (const float*)d_in[11];
    const float* ln2_b = (const float*)d_in[12];
    float* out = (float*)d_out;

    unsigned short* WtAll = (unsigned short*)d_ws;    // [4][512][512] bf16
    unsigned short* h_bf  = WtAll + 4 * 262144;       // [8192][512]
    unsigned short* Qb    = h_bf + 4194304;           // [64][1024][64]
    unsigned short* Kb    = Qb + 4194304;
    unsigned short* Vtg   = Kb + 4194304;             // [64][64][1024] transposed
    unsigned short* Ob    = Vtg + 4194304;            // [8192][512]
    float* qsq = (float*)(Ob + 4194304);              // [65536]
    float* ksq = qsq + 65536;

    // 1) weights -> bf16^T  +  LN1 -> bf16 (fused launch, wave-per-row LN)
    prep_kernel<<<256 + M_ROWS / 4, 256, 0, stream>>>(Wq, Wk, Wv, Wo, WtAll,
                                                      x, ln1_g, ln1_b, h_bf);

    // 2) fused QKV projection (N=1536) + coalesced scatter + sum-squares
    gemm128<1, 128><<<768, 256, 0, stream>>>(h_bf, WtAll, bq, bk, bv,
                                             Qb, Kb, Vtg, qsq, ksq);

    // 3) MFMA distance attention -> Ob (v5b: 32 q/wave, 2 blocks/CU)
    attn_kernel<<<512, 256, 0, stream>>>(Qb, Kb, Vtg, qsq, ksq, Ob);

    // 4) fused output projection + residual + LN2 -> out
    projln_kernel<<<256, 256, 0, stream>>>(Ob, WtAll + 3 * 262144, bo,
                                           x, ln2_g, ln2_b, out);
}